// Round 3
// baseline (484.750 us; speedup 1.0000x reference)
//
#include <hip/hip_runtime.h>
#include <math.h>

// B=16 P=16 I=16 L=64 D=128 F=128 C=1024
#define Bb 16
#define Pp 16
#define Ii 16
#define Ll 64
#define Dd 128
#define Ff 128
#define Cc 1024

static __device__ __forceinline__ float dot4(float4 a, float4 b) {
    return a.x*b.x + a.y*b.y + a.z*b.z + a.w*b.w;
}

// ---------------- Kernel 1: masked mean over L + conv projection ----------
// grid = B*P*I = 4096 blocks, 256 threads
__global__ __launch_bounds__(256) void k_mean_conv(
    const float* __restrict__ path_emb, const int* __restrict__ path_len,
    const float* __restrict__ conv_w, const float* __restrict__ conv_b,
    float* __restrict__ inst)
{
    int bpi = blockIdx.x;
    int t = threadIdx.x;
    int len = path_len[bpi];
    const float4* base = (const float4*)(path_emb + (size_t)bpi * Ll * Dd);
    int quad = t & 31;      // which float4 of the 128-float row
    int lr = t >> 5;        // 0..7 row group
    float4 acc = make_float4(0.f, 0.f, 0.f, 0.f);
    for (int l = lr; l < len; l += 8) {
        float4 v = base[l * 32 + quad];
        acc.x += v.x; acc.y += v.y; acc.z += v.z; acc.w += v.w;
    }
    __shared__ float4 red[256];
    __shared__ float4 mean4[32];
    red[t] = acc;
    __syncthreads();
    if (t < 32) {
        float4 s = red[t];
#pragma unroll
        for (int g = 1; g < 8; ++g) {
            float4 v = red[t + 32 * g];
            s.x += v.x; s.y += v.y; s.z += v.z; s.w += v.w;
        }
        float inv = 1.0f / (float)len;
        s.x *= inv; s.y *= inv; s.z *= inv; s.w *= inv;
        mean4[t] = s;
    }
    __syncthreads();
    if (t < 128) {
        const float4* w = (const float4*)(conv_w + (size_t)t * Dd);
        float a = conv_b[t];
#pragma unroll 8
        for (int dq = 0; dq < 32; ++dq) a += dot4(mean4[dq], w[dq]);
        inst[(size_t)bpi * Ff + t] = a;
    }
}

// ---------------- Kernel 2a: pia QKV projection (wide-parallel GEMM) -----
// M = B*P*I = 4096 rows of inst, N = 384. grid = 256 * 24 = 6144 blocks.
// One 16-row x-chunk (== one bp, since I==16) x one 16-row w-chunk per block.
// Lane-fast over weight rows: 16 distinct rows (256B) per load instr.
__global__ __launch_bounds__(256) void k_pia_qkv(
    const float* __restrict__ inst,
    const float* __restrict__ in_w, const float* __restrict__ in_b,
    float* __restrict__ qkv)
{
    int blk = blockIdx.x;
    int mc = blk / 24, jc = blk % 24;
    int t = threadIdx.x;
    int il = t >> 4;         // local x row 0..15
    int jl = t & 15;         // lane-fast over weight rows
    int row = mc * 16 + il;  // global inst row (bpi)
    int jg = jc * 16 + jl;   // qkv row 0..383
    const float4* x4 = (const float4*)(inst) + (size_t)row * 32;
    const float4* w4 = (const float4*)(in_w) + (size_t)jg * 32;
    float a = in_b[jg];
#pragma unroll 8
    for (int dq = 0; dq < 32; ++dq) a += dot4(x4[dq], w4[dq]);
    qkv[(size_t)row * 384 + jg] = a;
}

// ---------------- Kernel 2b: pia attention + mean + out proj -> meta -----
// grid = B*P = 256 blocks, 256 threads
__global__ __launch_bounds__(256) void k_pia_post(
    const float* __restrict__ qkv,
    const float* __restrict__ out_w, const float* __restrict__ out_b,
    float* __restrict__ meta)
{
    __shared__ float4 qs[16 * 33];
    __shared__ float4 ks[16 * 33];
    __shared__ float4 vs[16 * 33];
    __shared__ float Ss[16 * 17];
    __shared__ float wj[16];
    __shared__ float4 z4[32];
    int t = threadIdx.x, bp = blockIdx.x;
    float* vsf = (float*)vs;

    // stage qkv[bp] (16 x 384 floats = 16 x 96 float4) into padded LDS tiles
    const float4* src = (const float4*)(qkv + (size_t)bp * 6144);
    for (int idx = t; idx < 1536; idx += 256) {
        int i = idx / 96, q = idx - i * 96;
        float4 v = src[idx];
        if (q < 32)       qs[i * 33 + q]        = v;
        else if (q < 64)  ks[i * 33 + (q - 32)] = v;
        else              vs[i * 33 + (q - 64)] = v;
    }
    __syncthreads();

    // S = q k^T / sqrt(128)
    {
        int si = t >> 4, sj = t & 15;
        float s = 0.f;
#pragma unroll 8
        for (int dq = 0; dq < 32; ++dq)
            s += dot4(qs[si * 33 + dq], ks[sj * 33 + dq]);
        Ss[si * 17 + sj] = s * 0.08838834764831843f;
    }
    __syncthreads();
    // softmax rows
    if (t < 16) {
        float mx = -1e30f;
        for (int j = 0; j < 16; ++j) mx = fmaxf(mx, Ss[t * 17 + j]);
        float e[16]; float sum = 0.f;
        for (int j = 0; j < 16; ++j) { e[j] = expf(Ss[t * 17 + j] - mx); sum += e[j]; }
        float inv = 1.0f / sum;
        for (int j = 0; j < 16; ++j) Ss[t * 17 + j] = e[j] * inv;
    }
    __syncthreads();
    // column mean of attn (mean over i commutes through attn@v and out proj)
    if (t < 16) {
        float s = 0.f;
        for (int i2 = 0; i2 < 16; ++i2) s += Ss[i2 * 17 + t];
        wj[t] = s * (1.0f / 16.0f);
    }
    __syncthreads();
    // z[d] = sum_j wj[j] * v[j][d]
    if (t < 128) {
        float s = 0.f;
#pragma unroll
        for (int j = 0; j < 16; ++j) s += wj[j] * vsf[j * 132 + t];
        ((float*)z4)[t] = s;
    }
    __syncthreads();
    // meta[f] = z . out_w[f] + out_b[f]  (one weight row per lane)
    if (t < 128) {
        const float4* w = (const float4*)(out_w) + (size_t)t * 32;
        float a = out_b[t];
#pragma unroll 8
        for (int dq = 0; dq < 32; ++dq) a += dot4(z4[dq], w[dq]);
        meta[(size_t)bp * Ff + t] = a;
    }
}

// ---------------- Kernel 3a: mpa QKV projection (wide-parallel GEMM) -----
// grid = B * 24 = 384 blocks, 256 threads; block = (b, 16-row chunk of in_w)
// qkv layout: [b][i(16)][row(384)]
__global__ __launch_bounds__(256) void k_mpa_qkv(
    const float* __restrict__ meta,
    const float* __restrict__ in_w, const float* __restrict__ in_b,
    float* __restrict__ qkv)
{
    int blk = blockIdx.x;
    int b = blk / 24, jc = blk % 24;
    int t = threadIdx.x;
    int i = t >> 4;        // 0..15 input row
    int jl = t & 15;       // lane-fast over weight rows -> 16 distinct rows/instr
    int jg = jc * 16 + jl; // global qkv row 0..383
    const float4* x4 = (const float4*)(meta) + (size_t)b * 512 + i * 32;
    const float4* w4 = (const float4*)(in_w) + (size_t)jg * 32;
    float a = in_b[jg];
#pragma unroll 8
    for (int dq = 0; dq < 32; ++dq) a += dot4(x4[dq], w4[dq]);
    qkv[(size_t)b * 6144 + i * 384 + jg] = a;
}

// ---------------- Kernel 3b: mpa attention + qia + base, per b ----------
// grid = B = 16 blocks, 256 threads. One weight row per lane everywhere.
__global__ __launch_bounds__(256) void k_mpa_post(
    const float* __restrict__ qkv, const float* __restrict__ meta,
    const float* __restrict__ query,
    const float* __restrict__ out_w, const float* __restrict__ out_b,
    const float* __restrict__ qia_in_w, const float* __restrict__ qia_in_b,
    const float* __restrict__ qia_out_w, const float* __restrict__ qia_out_b,
    const float* __restrict__ score_w, const float* __restrict__ score_b,
    float* __restrict__ basev)
{
    __shared__ float4 qs[16 * 33];
    __shared__ float4 ks[16 * 33];
    __shared__ float4 vs[16 * 33];
    __shared__ float Ss[16 * 17];
    __shared__ float wj[16];
    __shared__ float4 z4[32];
    __shared__ float4 mm4[32];
    __shared__ float v1s[128];
    __shared__ float4 tq4[32];
    __shared__ float v2s[128];
    __shared__ float red[128];
    int t = threadIdx.x, b = blockIdx.x;
    float* vsf = (float*)vs;

    // stage qkv[b] (16 x 384) into q/k/v LDS tiles (padded rows of 33 float4)
    const float4* src = (const float4*)(qkv + (size_t)b * 6144);
    for (int idx = t; idx < 1536; idx += 256) {
        int i = idx / 96, q = idx - i * 96;
        float4 v = src[idx];
        if (q < 32)       qs[i * 33 + q]        = v;
        else if (q < 64)  ks[i * 33 + (q - 32)] = v;
        else              vs[i * 33 + (q - 64)] = v;
    }
    // mm[d] = mean_p meta[b][p][d] (global, coalesced per p)
    float mmacc = 0.f;
    if (t < 128) {
#pragma unroll
        for (int p = 0; p < 16; ++p) mmacc += meta[(size_t)b * 2048 + p * 128 + t];
        mmacc *= (1.0f / 16.0f);
    }
    __syncthreads();

    // S = q k^T / sqrt(128)
    {
        int si = t >> 4, sj = t & 15;
        float s = 0.f;
#pragma unroll 8
        for (int dq = 0; dq < 32; ++dq)
            s += dot4(qs[si * 33 + dq], ks[sj * 33 + dq]);
        Ss[si * 17 + sj] = s * 0.08838834764831843f;
    }
    if (t < 128) ((float*)mm4)[t] = mmacc;
    __syncthreads();
    // softmax rows
    if (t < 16) {
        float mx = -1e30f;
        for (int j = 0; j < 16; ++j) mx = fmaxf(mx, Ss[t * 17 + j]);
        float e[16]; float sum = 0.f;
        for (int j = 0; j < 16; ++j) { e[j] = expf(Ss[t * 17 + j] - mx); sum += e[j]; }
        float inv = 1.0f / sum;
        for (int j = 0; j < 16; ++j) Ss[t * 17 + j] = e[j] * inv;
    }
    __syncthreads();
    // column mean of attn
    if (t < 16) {
        float s = 0.f;
        for (int i2 = 0; i2 < 16; ++i2) s += Ss[i2 * 17 + t];
        wj[t] = s * (1.0f / 16.0f);
    }
    __syncthreads();
    // z[d] = sum_j wj[j] * v[j][d]
    if (t < 128) {
        float s = 0.f;
#pragma unroll
        for (int j = 0; j < 16; ++j) s += wj[j] * vsf[j * 132 + t];
        ((float*)z4)[t] = s;
    }
    __syncthreads();

    // phase A: t<128 -> v1[f] = z . out_w[f] + out_b[f]
    //          t>=128 -> tq[f] = mm . qia_in_w[256+f] + qia_in_b[256+f]
    if (t < 128) {
        const float4* w = (const float4*)(out_w) + (size_t)t * 32;
        float a = out_b[t];
#pragma unroll 8
        for (int dq = 0; dq < 32; ++dq) a += dot4(z4[dq], w[dq]);
        v1s[t] = a;
    } else {
        int f = t - 128;
        const float4* w = (const float4*)(qia_in_w) + (size_t)(256 + f) * 32;
        float a = qia_in_b[256 + f];
#pragma unroll 8
        for (int dq = 0; dq < 32; ++dq) a += dot4(mm4[dq], w[dq]);
        ((float*)tq4)[f] = a;
    }
    __syncthreads();
    // phase B: v2[f] = tq . qia_out_w[f] + qia_out_b[f]
    if (t < 128) {
        const float4* w = (const float4*)(qia_out_w) + (size_t)t * 32;
        float a = qia_out_b[t];
#pragma unroll 8
        for (int dq = 0; dq < 32; ++dq) a += dot4(tq4[dq], w[dq]);
        v2s[t] = a;
    }
    __syncthreads();
    // phase C: base[b] = q.sw0 + v1.sw1 + v2.sw2 + score_b
    if (t < 128) {
        red[t] = query[(size_t)b * Dd + t] * score_w[t]
               + v1s[t] * score_w[128 + t]
               + v2s[t] * score_w[256 + t];
    }
    __syncthreads();
    for (int s = 64; s > 0; s >>= 1) {
        if (t < s) red[t] += red[t + s];
        __syncthreads();
    }
    if (t == 0) basev[b] = red[0] + score_b[0];
}

// ---------------- Kernel 4a: cand scores -> exp, per-b sum ---------------
// grid = B*P*8 = 2048 blocks, 256 threads; each block does 128 candidates
__global__ __launch_bounds__(256) void k_score(
    const float* __restrict__ cand_emb, const int* __restrict__ cand_len,
    const float* __restrict__ score_w, const float* __restrict__ basev,
    float* __restrict__ eout, float* __restrict__ sumexp)
{
    int blk = blockIdx.x;
    int chunk = blk & 7;
    int bp = blk >> 3;
    int b = bp >> 4;
    int t = threadIdx.x;
    int quad = t & 31, cl = t >> 5;   // 8 candidates concurrently
    float4 swq = ((const float4*)(score_w + 384))[quad];
    float bb = basev[b];
    int clen = cand_len[bp];
    const float4* cbase = (const float4*)(cand_emb + ((size_t)bp * Cc + chunk * 128) * Dd);
    float lsum = 0.f;
#pragma unroll 4
    for (int it = 0; it < 16; ++it) {
        int c = cl + it * 8;          // local candidate 0..127
        float4 v = cbase[(size_t)c * 32 + quad];
        float part = dot4(v, swq);
        part += __shfl_xor(part, 16);
        part += __shfl_xor(part, 8);
        part += __shfl_xor(part, 4);
        part += __shfl_xor(part, 2);
        part += __shfl_xor(part, 1);
        int gc = chunk * 128 + c;
        float e = (gc < clen) ? expf(part + bb) : 0.0f;
        if (quad == 0) {
            eout[(size_t)bp * Cc + gc] = e;
            lsum += e;
        }
    }
    __shared__ float red[256];
    red[t] = lsum;
    __syncthreads();
    for (int s = 128; s > 0; s >>= 1) {
        if (t < s) red[t] += red[t + s];
        __syncthreads();
    }
    if (t == 0) atomicAdd(&sumexp[b], red[0]);
}

// ---------------- Kernel 4b: normalize ------------------------------------
// grid = 256 blocks * 256 threads, one float4 each (65536 float4 total)
__global__ __launch_bounds__(256) void k_norm(
    float* __restrict__ out, const float* __restrict__ sumexp)
{
    int idx = blockIdx.x * 256 + threadIdx.x;
    int b = idx >> 12;  // 4096 float4 per batch
    float inv = 1.0f / sumexp[b];
    float4* o4 = (float4*)out;
    float4 v = o4[idx];
    v.x *= inv; v.y *= inv; v.z *= inv; v.w *= inv;
    o4[idx] = v;
}

extern "C" void kernel_launch(void* const* d_in, const int* in_sizes, int n_in,
                              void* d_out, int out_size, void* d_ws, size_t ws_size,
                              hipStream_t stream)
{
    const float* query    = (const float*)d_in[0];
    const float* path_emb = (const float*)d_in[1];
    const int*   path_len = (const int*)  d_in[2];
    const float* cand_emb = (const float*)d_in[3];
    const int*   cand_len = (const int*)  d_in[4];
    const float* conv_w   = (const float*)d_in[5];
    const float* conv_b   = (const float*)d_in[6];
    const float* pia_in_w = (const float*)d_in[7];
    const float* pia_in_b = (const float*)d_in[8];
    const float* pia_out_w= (const float*)d_in[9];
    const float* pia_out_b= (const float*)d_in[10];
    const float* mpa_in_w = (const float*)d_in[11];
    const float* mpa_in_b = (const float*)d_in[12];
    const float* mpa_out_w= (const float*)d_in[13];
    const float* mpa_out_b= (const float*)d_in[14];
    const float* qia_in_w = (const float*)d_in[15];
    const float* qia_in_b = (const float*)d_in[16];
    const float* qia_out_w= (const float*)d_in[17];
    const float* qia_out_b= (const float*)d_in[18];
    const float* score_w  = (const float*)d_in[19];
    const float* score_b  = (const float*)d_in[20];
    float* out = (float*)d_out;

    float* ws      = (float*)d_ws;
    float* inst    = ws;                        // B*P*I*F = 524288 floats
    float* meta    = ws + 524288;               // B*P*F   = 32768
    float* basev   = ws + 524288 + 32768;       // 16
    float* sumexp  = basev + 16;                // 16
    float* qkv_pia = sumexp + 16;               // 4096*384 = 1572864
    float* qkv_mpa = ws;                        // 16*16*384, reuses dead inst

    hipMemsetAsync(sumexp, 0, Bb * sizeof(float), stream);

    k_mean_conv<<<Bb * Pp * Ii, 256, 0, stream>>>(path_emb, path_len, conv_w, conv_b, inst);
    k_pia_qkv<<<256 * 24, 256, 0, stream>>>(inst, pia_in_w, pia_in_b, qkv_pia);
    k_pia_post<<<Bb * Pp, 256, 0, stream>>>(qkv_pia, pia_out_w, pia_out_b, meta);
    k_mpa_qkv<<<Bb * 24, 256, 0, stream>>>(meta, mpa_in_w, mpa_in_b, qkv_mpa);
    k_mpa_post<<<Bb, 256, 0, stream>>>(qkv_mpa, meta, query,
                                       mpa_out_w, mpa_out_b,
                                       qia_in_w, qia_in_b, qia_out_w, qia_out_b,
                                       score_w, score_b, basev);
    k_score<<<Bb * Pp * 8, 256, 0, stream>>>(cand_emb, cand_len, score_w, basev, out, sumexp);
    k_norm<<<256, 256, 0, stream>>>(out, sumexp);
}

// Round 4
// 388.938 us; speedup vs baseline: 1.2463x; 1.2463x over previous
//
#include <hip/hip_runtime.h>
#include <math.h>

// B=16 P=16 I=16 L=64 D=128 F=128 C=1024
#define Bb 16
#define Pp 16
#define Ii 16
#define Ll 64
#define Dd 128
#define Ff 128
#define Cc 1024

static __device__ __forceinline__ float dot4(float4 a, float4 b) {
    return a.x*b.x + a.y*b.y + a.z*b.z + a.w*b.w;
}

// ---------------- Kernel 1: masked mean over L + conv projection ----------
// grid = B*P*I = 4096 blocks, 256 threads
__global__ __launch_bounds__(256) void k_mean_conv(
    const float* __restrict__ path_emb, const int* __restrict__ path_len,
    const float* __restrict__ conv_w, const float* __restrict__ conv_b,
    float* __restrict__ inst)
{
    int bpi = blockIdx.x;
    int t = threadIdx.x;
    int len = path_len[bpi];
    const float4* base = (const float4*)(path_emb + (size_t)bpi * Ll * Dd);
    int quad = t & 31;      // which float4 of the 128-float row
    int lr = t >> 5;        // 0..7 row group
    float4 acc = make_float4(0.f, 0.f, 0.f, 0.f);
    for (int l = lr; l < len; l += 8) {
        float4 v = base[l * 32 + quad];
        acc.x += v.x; acc.y += v.y; acc.z += v.z; acc.w += v.w;
    }
    __shared__ float4 red[256];
    __shared__ float4 mean4[32];
    red[t] = acc;
    __syncthreads();
    if (t < 32) {
        float4 s = red[t];
#pragma unroll
        for (int g = 1; g < 8; ++g) {
            float4 v = red[t + 32 * g];
            s.x += v.x; s.y += v.y; s.z += v.z; s.w += v.w;
        }
        float inv = 1.0f / (float)len;
        s.x *= inv; s.y *= inv; s.z *= inv; s.w *= inv;
        mean4[t] = s;
    }
    __syncthreads();
    if (t < 128) {
        const float4* w = (const float4*)(conv_w + (size_t)t * Dd);
        float a = conv_b[t];
#pragma unroll 8
        for (int dq = 0; dq < 32; ++dq) a += dot4(mean4[dq], w[dq]);
        inst[(size_t)bpi * Ff + t] = a;
    }
}

// ---------------- Generic tiled GEMM: C[M,N] = A[M,128] @ W[N,128]^T + b --
// Mtile=64, Ntile=96, 256 threads, micro-tile 4x6 per thread.
// LDS k4-major: As[k4][64] (pad 65), Ws[k4][96] (pad 97) -> compute reads
// are consecutive-float4-per-lane (conflict-free); global stage loads are
// coalesced (consecutive lanes = consecutive float4 of one row).
__global__ __launch_bounds__(256) void k_gemm(
    const float* __restrict__ A, const float* __restrict__ W,
    const float* __restrict__ bias, float* __restrict__ C,
    int N, int nbn)
{
    __shared__ float4 As[32 * 65];
    __shared__ float4 Wsh[32 * 97];
    int t = threadIdx.x;
    int bm = blockIdx.x / nbn, bn = blockIdx.x % nbn;

    // stage A tile (64 rows x 32 f4), transpose to k4-major
    {
        const float4* Ag = (const float4*)A + (size_t)(bm * 64) * 32;
        int k4 = t & 31;
        int m0 = (t >> 5) * 8;
#pragma unroll
        for (int r = 0; r < 8; ++r)
            As[k4 * 65 + m0 + r] = Ag[(size_t)(m0 + r) * 32 + k4];
    }
    // stage W tile (96 rows x 32 f4), transpose to k4-major
    {
        const float4* Wg = (const float4*)W + (size_t)(bn * 96) * 32;
        int k4 = t & 31;
        int n0 = (t >> 5) * 12;
#pragma unroll
        for (int r = 0; r < 12; ++r)
            Wsh[k4 * 97 + n0 + r] = Wg[(size_t)(n0 + r) * 32 + k4];
    }
    __syncthreads();

    int tn = t & 15;   // lane-fast over n -> coalesced C stores
    int tm = t >> 4;
    float acc[4][6];
#pragma unroll
    for (int i = 0; i < 4; ++i)
#pragma unroll
        for (int j = 0; j < 6; ++j) acc[i][j] = 0.f;

#pragma unroll 2
    for (int k4 = 0; k4 < 32; ++k4) {
        float4 a[4], b[6];
#pragma unroll
        for (int i = 0; i < 4; ++i) a[i] = As[k4 * 65 + tm + 16 * i];
#pragma unroll
        for (int j = 0; j < 6; ++j) b[j] = Wsh[k4 * 97 + tn + 16 * j];
#pragma unroll
        for (int i = 0; i < 4; ++i)
#pragma unroll
            for (int j = 0; j < 6; ++j)
                acc[i][j] += dot4(a[i], b[j]);
    }

#pragma unroll
    for (int i = 0; i < 4; ++i) {
        int m = bm * 64 + tm + 16 * i;
#pragma unroll
        for (int j = 0; j < 6; ++j) {
            int n = bn * 96 + tn + 16 * j;
            C[(size_t)m * N + n] = acc[i][j] + bias[n];
        }
    }
}

// ---------------- Kernel 2b: pia attention + mean + out proj -> meta -----
// grid = B*P = 256 blocks, 256 threads. out_w staged in LDS (f4-transposed).
__global__ __launch_bounds__(256) void k_pia_post(
    const float* __restrict__ qkv,
    const float* __restrict__ out_w, const float* __restrict__ out_b,
    float* __restrict__ meta)
{
    __shared__ float4 qs[16 * 33];
    __shared__ float4 ks[16 * 33];
    __shared__ float4 vs[16 * 33];
    __shared__ float4 ows[32 * 132];   // [k4][f] f4-transposed out_w
    __shared__ float Ss[16 * 17];
    __shared__ float wj[16];
    __shared__ float4 z4[32];
    int t = threadIdx.x, bp = blockIdx.x;
    float* vsf = (float*)vs;

    // stage qkv[bp] (16 x 384 floats = 16 x 96 float4) into padded LDS tiles
    const float4* src = (const float4*)(qkv + (size_t)bp * 6144);
    for (int idx = t; idx < 1536; idx += 256) {
        int i = idx / 96, q = idx - i * 96;
        float4 v = src[idx];
        if (q < 32)       qs[i * 33 + q]        = v;
        else if (q < 64)  ks[i * 33 + (q - 32)] = v;
        else              vs[i * 33 + (q - 64)] = v;
    }
    // stage out_w (128x128 = 4096 f4), coalesced global, f4-transposed LDS
    {
        const float4* owg = (const float4*)out_w;
#pragma unroll
        for (int r = 0; r < 16; ++r) {
            int idx = t + 256 * r;
            int f = idx >> 5, k4 = idx & 31;
            ows[k4 * 132 + f] = owg[idx];
        }
    }
    __syncthreads();

    // S = q k^T / sqrt(128)
    {
        int si = t >> 4, sj = t & 15;
        float s = 0.f;
#pragma unroll 8
        for (int dq = 0; dq < 32; ++dq)
            s += dot4(qs[si * 33 + dq], ks[sj * 33 + dq]);
        Ss[si * 17 + sj] = s * 0.08838834764831843f;
    }
    __syncthreads();
    // softmax rows
    if (t < 16) {
        float mx = -1e30f;
        for (int j = 0; j < 16; ++j) mx = fmaxf(mx, Ss[t * 17 + j]);
        float e[16]; float sum = 0.f;
        for (int j = 0; j < 16; ++j) { e[j] = expf(Ss[t * 17 + j] - mx); sum += e[j]; }
        float inv = 1.0f / sum;
        for (int j = 0; j < 16; ++j) Ss[t * 17 + j] = e[j] * inv;
    }
    __syncthreads();
    // column mean of attn (mean over i commutes through attn@v and out proj)
    if (t < 16) {
        float s = 0.f;
        for (int i2 = 0; i2 < 16; ++i2) s += Ss[i2 * 17 + t];
        wj[t] = s * (1.0f / 16.0f);
    }
    __syncthreads();
    // z[d] = sum_j wj[j] * v[j][d]
    if (t < 128) {
        float s = 0.f;
#pragma unroll
        for (int j = 0; j < 16; ++j) s += wj[j] * vsf[j * 132 + t];
        ((float*)z4)[t] = s;
    }
    __syncthreads();
    // meta[f] = z . out_w[f] + out_b[f]  (LDS reads consecutive-f4-per-lane)
    if (t < 128) {
        float a = out_b[t];
#pragma unroll 8
        for (int k4 = 0; k4 < 32; ++k4) a += dot4(z4[k4], ows[k4 * 132 + t]);
        meta[(size_t)bp * Ff + t] = a;
    }
}

// ---------------- Kernel 3b: mpa attention + qia + base, per b ----------
// grid = B = 16 blocks, 256 threads.
__global__ __launch_bounds__(256) void k_mpa_post(
    const float* __restrict__ qkv, const float* __restrict__ meta,
    const float* __restrict__ query,
    const float* __restrict__ out_w, const float* __restrict__ out_b,
    const float* __restrict__ qia_in_w, const float* __restrict__ qia_in_b,
    const float* __restrict__ qia_out_w, const float* __restrict__ qia_out_b,
    const float* __restrict__ score_w, const float* __restrict__ score_b,
    float* __restrict__ basev)
{
    __shared__ float4 qs[16 * 33];
    __shared__ float4 ks[16 * 33];
    __shared__ float4 vs[16 * 33];
    __shared__ float Ss[16 * 17];
    __shared__ float wj[16];
    __shared__ float4 z4[32];
    __shared__ float4 mm4[32];
    __shared__ float v1s[128];
    __shared__ float4 tq4[32];
    __shared__ float v2s[128];
    __shared__ float red[128];
    int t = threadIdx.x, b = blockIdx.x;
    float* vsf = (float*)vs;

    // stage qkv[b] (16 x 384) into q/k/v LDS tiles (padded rows of 33 float4)
    const float4* src = (const float4*)(qkv + (size_t)b * 6144);
    for (int idx = t; idx < 1536; idx += 256) {
        int i = idx / 96, q = idx - i * 96;
        float4 v = src[idx];
        if (q < 32)       qs[i * 33 + q]        = v;
        else if (q < 64)  ks[i * 33 + (q - 32)] = v;
        else              vs[i * 33 + (q - 64)] = v;
    }
    // mm[d] = mean_p meta[b][p][d] (global, coalesced per p)
    float mmacc = 0.f;
    if (t < 128) {
#pragma unroll
        for (int p = 0; p < 16; ++p) mmacc += meta[(size_t)b * 2048 + p * 128 + t];
        mmacc *= (1.0f / 16.0f);
    }
    __syncthreads();

    // S = q k^T / sqrt(128)
    {
        int si = t >> 4, sj = t & 15;
        float s = 0.f;
#pragma unroll 8
        for (int dq = 0; dq < 32; ++dq)
            s += dot4(qs[si * 33 + dq], ks[sj * 33 + dq]);
        Ss[si * 17 + sj] = s * 0.08838834764831843f;
    }
    if (t < 128) ((float*)mm4)[t] = mmacc;
    __syncthreads();
    // softmax rows
    if (t < 16) {
        float mx = -1e30f;
        for (int j = 0; j < 16; ++j) mx = fmaxf(mx, Ss[t * 17 + j]);
        float e[16]; float sum = 0.f;
        for (int j = 0; j < 16; ++j) { e[j] = expf(Ss[t * 17 + j] - mx); sum += e[j]; }
        float inv = 1.0f / sum;
        for (int j = 0; j < 16; ++j) Ss[t * 17 + j] = e[j] * inv;
    }
    __syncthreads();
    // column mean of attn
    if (t < 16) {
        float s = 0.f;
        for (int i2 = 0; i2 < 16; ++i2) s += Ss[i2 * 17 + t];
        wj[t] = s * (1.0f / 16.0f);
    }
    __syncthreads();
    // z[d] = sum_j wj[j] * v[j][d]
    if (t < 128) {
        float s = 0.f;
#pragma unroll
        for (int j = 0; j < 16; ++j) s += wj[j] * vsf[j * 132 + t];
        ((float*)z4)[t] = s;
    }
    __syncthreads();

    // phase A: t<128 -> v1[f] = z . out_w[f] + out_b[f]
    //          t>=128 -> tq[f] = mm . qia_in_w[256+f] + qia_in_b[256+f]
    if (t < 128) {
        const float4* w = (const float4*)(out_w) + (size_t)t * 32;
        float a = out_b[t];
#pragma unroll 8
        for (int dq = 0; dq < 32; ++dq) a += dot4(z4[dq], w[dq]);
        v1s[t] = a;
    } else {
        int f = t - 128;
        const float4* w = (const float4*)(qia_in_w) + (size_t)(256 + f) * 32;
        float a = qia_in_b[256 + f];
#pragma unroll 8
        for (int dq = 0; dq < 32; ++dq) a += dot4(mm4[dq], w[dq]);
        ((float*)tq4)[f] = a;
    }
    __syncthreads();
    // phase B: v2[f] = tq . qia_out_w[f] + qia_out_b[f]
    if (t < 128) {
        const float4* w = (const float4*)(qia_out_w) + (size_t)t * 32;
        float a = qia_out_b[t];
#pragma unroll 8
        for (int dq = 0; dq < 32; ++dq) a += dot4(tq4[dq], w[dq]);
        v2s[t] = a;
    }
    __syncthreads();
    // phase C: base[b] = q.sw0 + v1.sw1 + v2.sw2 + score_b
    if (t < 128) {
        red[t] = query[(size_t)b * Dd + t] * score_w[t]
               + v1s[t] * score_w[128 + t]
               + v2s[t] * score_w[256 + t];
    }
    __syncthreads();
    for (int s = 64; s > 0; s >>= 1) {
        if (t < s) red[t] += red[t + s];
        __syncthreads();
    }
    if (t == 0) basev[b] = red[0] + score_b[0];
}

// ---------------- Kernel 4a: cand scores -> exp, per-b sum ---------------
// grid = B*P*8 = 2048 blocks, 256 threads; each block does 128 candidates
__global__ __launch_bounds__(256) void k_score(
    const float* __restrict__ cand_emb, const int* __restrict__ cand_len,
    const float* __restrict__ score_w, const float* __restrict__ basev,
    float* __restrict__ eout, float* __restrict__ sumexp)
{
    int blk = blockIdx.x;
    int chunk = blk & 7;
    int bp = blk >> 3;
    int b = bp >> 4;
    int t = threadIdx.x;
    int quad = t & 31, cl = t >> 5;   // 8 candidates concurrently
    float4 swq = ((const float4*)(score_w + 384))[quad];
    float bb = basev[b];
    int clen = cand_len[bp];
    const float4* cbase = (const float4*)(cand_emb + ((size_t)bp * Cc + chunk * 128) * Dd);
    float lsum = 0.f;
#pragma unroll 4
    for (int it = 0; it < 16; ++it) {
        int c = cl + it * 8;          // local candidate 0..127
        float4 v = cbase[(size_t)c * 32 + quad];
        float part = dot4(v, swq);
        part += __shfl_xor(part, 16);
        part += __shfl_xor(part, 8);
        part += __shfl_xor(part, 4);
        part += __shfl_xor(part, 2);
        part += __shfl_xor(part, 1);
        int gc = chunk * 128 + c;
        float e = (gc < clen) ? expf(part + bb) : 0.0f;
        if (quad == 0) {
            eout[(size_t)bp * Cc + gc] = e;
            lsum += e;
        }
    }
    __shared__ float red[256];
    red[t] = lsum;
    __syncthreads();
    for (int s = 128; s > 0; s >>= 1) {
        if (t < s) red[t] += red[t + s];
        __syncthreads();
    }
    if (t == 0) atomicAdd(&sumexp[b], red[0]);
}

// ---------------- Kernel 4b: normalize ------------------------------------
// grid = 256 blocks * 256 threads, one float4 each (65536 float4 total)
__global__ __launch_bounds__(256) void k_norm(
    float* __restrict__ out, const float* __restrict__ sumexp)
{
    int idx = blockIdx.x * 256 + threadIdx.x;
    int b = idx >> 12;  // 4096 float4 per batch
    float inv = 1.0f / sumexp[b];
    float4* o4 = (float4*)out;
    float4 v = o4[idx];
    v.x *= inv; v.y *= inv; v.z *= inv; v.w *= inv;
    o4[idx] = v;
}

extern "C" void kernel_launch(void* const* d_in, const int* in_sizes, int n_in,
                              void* d_out, int out_size, void* d_ws, size_t ws_size,
                              hipStream_t stream)
{
    const float* query    = (const float*)d_in[0];
    const float* path_emb = (const float*)d_in[1];
    const int*   path_len = (const int*)  d_in[2];
    const float* cand_emb = (const float*)d_in[3];
    const int*   cand_len = (const int*)  d_in[4];
    const float* conv_w   = (const float*)d_in[5];
    const float* conv_b   = (const float*)d_in[6];
    const float* pia_in_w = (const float*)d_in[7];
    const float* pia_in_b = (const float*)d_in[8];
    const float* pia_out_w= (const float*)d_in[9];
    const float* pia_out_b= (const float*)d_in[10];
    const float* mpa_in_w = (const float*)d_in[11];
    const float* mpa_in_b = (const float*)d_in[12];
    const float* mpa_out_w= (const float*)d_in[13];
    const float* mpa_out_b= (const float*)d_in[14];
    const float* qia_in_w = (const float*)d_in[15];
    const float* qia_in_b = (const float*)d_in[16];
    const float* qia_out_w= (const float*)d_in[17];
    const float* qia_out_b= (const float*)d_in[18];
    const float* score_w  = (const float*)d_in[19];
    const float* score_b  = (const float*)d_in[20];
    float* out = (float*)d_out;

    float* ws      = (float*)d_ws;
    float* inst    = ws;                        // B*P*I*F = 524288 floats
    float* meta    = ws + 524288;               // B*P*F   = 32768
    float* basev   = ws + 524288 + 32768;       // 16
    float* sumexp  = basev + 16;                // 16
    float* qkv_pia = sumexp + 16;               // 4096*384 = 1572864
    float* qkv_mpa = qkv_pia + 1572864;         // 256*384  = 98304

    hipMemsetAsync(sumexp, 0, Bb * sizeof(float), stream);

    k_mean_conv<<<Bb * Pp * Ii, 256, 0, stream>>>(path_emb, path_len, conv_w, conv_b, inst);
    // pia qkv: M=4096, N=384 -> 64 x 4 = 256 blocks
    k_gemm<<<64 * 4, 256, 0, stream>>>(inst, pia_in_w, pia_in_b, qkv_pia, 384, 4);
    k_pia_post<<<Bb * Pp, 256, 0, stream>>>(qkv_pia, pia_out_w, pia_out_b, meta);
    // mpa qkv: M=256, N=384 -> 4 x 4 = 16 blocks
    k_gemm<<<4 * 4, 256, 0, stream>>>(meta, mpa_in_w, mpa_in_b, qkv_mpa, 384, 4);
    k_mpa_post<<<Bb, 256, 0, stream>>>(qkv_mpa, meta, query,
                                       mpa_out_w, mpa_out_b,
                                       qia_in_w, qia_in_b, qia_out_w, qia_out_b,
                                       score_w, score_b, basev);
    k_score<<<Bb * Pp * 8, 256, 0, stream>>>(cand_emb, cand_len, score_w, basev, out, sumexp);
    k_norm<<<256, 256, 0, stream>>>(out, sumexp);
}

// Round 5
// 365.925 us; speedup vs baseline: 1.3247x; 1.0629x over previous
//
#include <hip/hip_runtime.h>
#include <math.h>

// B=16 P=16 I=16 L=64 D=128 F=128 C=1024
#define Bb 16
#define Pp 16
#define Ii 16
#define Ll 64
#define Dd 128
#define Ff 128
#define Cc 1024

static __device__ __forceinline__ float dot4(float4 a, float4 b) {
    return a.x*b.x + a.y*b.y + a.z*b.z + a.w*b.w;
}

// ---------------- Kernel 1: fused front end -------------------------------
// blocks 0..4095   : masked mean over L + conv projection (one bpi each)
// blocks 4096..6143: raw candidate dot scores (no base/exp yet — those
//                    don't depend on the attention chain)
// block 4096 also zeroes sumexp (consumed by k_exp_sum, 4 kernels later).
__global__ __launch_bounds__(256) void k_front(
    const float* __restrict__ path_emb, const int* __restrict__ path_len,
    const float* __restrict__ conv_w, const float* __restrict__ conv_b,
    const float* __restrict__ cand_emb, const float* __restrict__ score_w,
    float* __restrict__ inst, float* __restrict__ dots,
    float* __restrict__ sumexp)
{
    int blk = blockIdx.x;
    int t = threadIdx.x;
    if (blk < 4096) {
        // ---- masked mean + conv ----
        int bpi = blk;
        int len = path_len[bpi];
        const float4* base = (const float4*)(path_emb + (size_t)bpi * Ll * Dd);
        int quad = t & 31;      // which float4 of the 128-float row
        int lr = t >> 5;        // 0..7 row group
        float4 acc = make_float4(0.f, 0.f, 0.f, 0.f);
        for (int l = lr; l < len; l += 8) {
            float4 v = base[l * 32 + quad];
            acc.x += v.x; acc.y += v.y; acc.z += v.z; acc.w += v.w;
        }
        __shared__ float4 red[256];
        __shared__ float4 mean4[32];
        red[t] = acc;
        __syncthreads();
        if (t < 32) {
            float4 s = red[t];
#pragma unroll
            for (int g = 1; g < 8; ++g) {
                float4 v = red[t + 32 * g];
                s.x += v.x; s.y += v.y; s.z += v.z; s.w += v.w;
            }
            float inv = 1.0f / (float)len;
            s.x *= inv; s.y *= inv; s.z *= inv; s.w *= inv;
            mean4[t] = s;
        }
        __syncthreads();
        if (t < 128) {
            const float4* w = (const float4*)(conv_w + (size_t)t * Dd);
            float a = conv_b[t];
#pragma unroll 8
            for (int dq = 0; dq < 32; ++dq) a += dot4(mean4[dq], w[dq]);
            inst[(size_t)bpi * Ff + t] = a;
        }
    } else {
        // ---- candidate dot scores ----
        int blk2 = blk - 4096;
        if (blk2 == 0 && t < Bb) sumexp[t] = 0.f;
        int chunk = blk2 & 7;
        int bp = blk2 >> 3;
        int quad = t & 31, cl = t >> 5;   // 8 candidates concurrently
        float4 swq = ((const float4*)(score_w + 384))[quad];
        const float4* cbase = (const float4*)(cand_emb + ((size_t)bp * Cc + chunk * 128) * Dd);
#pragma unroll 4
        for (int it = 0; it < 16; ++it) {
            int c = cl + it * 8;          // local candidate 0..127
            float4 v = cbase[(size_t)c * 32 + quad];
            float part = dot4(v, swq);
            part += __shfl_xor(part, 16);
            part += __shfl_xor(part, 8);
            part += __shfl_xor(part, 4);
            part += __shfl_xor(part, 2);
            part += __shfl_xor(part, 1);
            if (quad == 0)
                dots[(size_t)bp * Cc + chunk * 128 + c] = part;
        }
    }
}

// ---------------- Generic tiled GEMM: C[M,N] = A[M,128] @ W[N,128]^T + b --
// Mtile=64, Ntile=96, 256 threads, micro-tile 4x6 per thread.
__global__ __launch_bounds__(256) void k_gemm(
    const float* __restrict__ A, const float* __restrict__ W,
    const float* __restrict__ bias, float* __restrict__ C,
    int N, int nbn)
{
    __shared__ float4 As[32 * 65];
    __shared__ float4 Wsh[32 * 97];
    int t = threadIdx.x;
    int bm = blockIdx.x / nbn, bn = blockIdx.x % nbn;

    {
        const float4* Ag = (const float4*)A + (size_t)(bm * 64) * 32;
        int k4 = t & 31;
        int m0 = (t >> 5) * 8;
#pragma unroll
        for (int r = 0; r < 8; ++r)
            As[k4 * 65 + m0 + r] = Ag[(size_t)(m0 + r) * 32 + k4];
    }
    {
        const float4* Wg = (const float4*)W + (size_t)(bn * 96) * 32;
        int k4 = t & 31;
        int n0 = (t >> 5) * 12;
#pragma unroll
        for (int r = 0; r < 12; ++r)
            Wsh[k4 * 97 + n0 + r] = Wg[(size_t)(n0 + r) * 32 + k4];
    }
    __syncthreads();

    int tn = t & 15;   // lane-fast over n -> coalesced C stores
    int tm = t >> 4;
    float acc[4][6];
#pragma unroll
    for (int i = 0; i < 4; ++i)
#pragma unroll
        for (int j = 0; j < 6; ++j) acc[i][j] = 0.f;

#pragma unroll 2
    for (int k4 = 0; k4 < 32; ++k4) {
        float4 a[4], b[6];
#pragma unroll
        for (int i = 0; i < 4; ++i) a[i] = As[k4 * 65 + tm + 16 * i];
#pragma unroll
        for (int j = 0; j < 6; ++j) b[j] = Wsh[k4 * 97 + tn + 16 * j];
#pragma unroll
        for (int i = 0; i < 4; ++i)
#pragma unroll
            for (int j = 0; j < 6; ++j)
                acc[i][j] += dot4(a[i], b[j]);
    }

#pragma unroll
    for (int i = 0; i < 4; ++i) {
        int m = bm * 64 + tm + 16 * i;
#pragma unroll
        for (int j = 0; j < 6; ++j) {
            int n = bn * 96 + tn + 16 * j;
            C[(size_t)m * N + n] = acc[i][j] + bias[n];
        }
    }
}

// ---------------- Kernel 2b: pia attention + mean + out proj -> meta -----
// grid = B*P = 256 blocks, 256 threads. out_w staged in LDS (f4-transposed).
__global__ __launch_bounds__(256) void k_pia_post(
    const float* __restrict__ qkv,
    const float* __restrict__ out_w, const float* __restrict__ out_b,
    float* __restrict__ meta)
{
    __shared__ float4 qs[16 * 33];
    __shared__ float4 ks[16 * 33];
    __shared__ float4 vs[16 * 33];
    __shared__ float4 ows[32 * 132];   // [k4][f] f4-transposed out_w
    __shared__ float Ss[16 * 17];
    __shared__ float wj[16];
    __shared__ float4 z4[32];
    int t = threadIdx.x, bp = blockIdx.x;
    float* vsf = (float*)vs;

    const float4* src = (const float4*)(qkv + (size_t)bp * 6144);
    for (int idx = t; idx < 1536; idx += 256) {
        int i = idx / 96, q = idx - i * 96;
        float4 v = src[idx];
        if (q < 32)       qs[i * 33 + q]        = v;
        else if (q < 64)  ks[i * 33 + (q - 32)] = v;
        else              vs[i * 33 + (q - 64)] = v;
    }
    {
        const float4* owg = (const float4*)out_w;
#pragma unroll
        for (int r = 0; r < 16; ++r) {
            int idx = t + 256 * r;
            int f = idx >> 5, k4 = idx & 31;
            ows[k4 * 132 + f] = owg[idx];
        }
    }
    __syncthreads();

    {
        int si = t >> 4, sj = t & 15;
        float s = 0.f;
#pragma unroll 8
        for (int dq = 0; dq < 32; ++dq)
            s += dot4(qs[si * 33 + dq], ks[sj * 33 + dq]);
        Ss[si * 17 + sj] = s * 0.08838834764831843f;
    }
    __syncthreads();
    if (t < 16) {
        float mx = -1e30f;
        for (int j = 0; j < 16; ++j) mx = fmaxf(mx, Ss[t * 17 + j]);
        float e[16]; float sum = 0.f;
        for (int j = 0; j < 16; ++j) { e[j] = expf(Ss[t * 17 + j] - mx); sum += e[j]; }
        float inv = 1.0f / sum;
        for (int j = 0; j < 16; ++j) Ss[t * 17 + j] = e[j] * inv;
    }
    __syncthreads();
    if (t < 16) {
        float s = 0.f;
        for (int i2 = 0; i2 < 16; ++i2) s += Ss[i2 * 17 + t];
        wj[t] = s * (1.0f / 16.0f);
    }
    __syncthreads();
    if (t < 128) {
        float s = 0.f;
#pragma unroll
        for (int j = 0; j < 16; ++j) s += wj[j] * vsf[j * 132 + t];
        ((float*)z4)[t] = s;
    }
    __syncthreads();
    if (t < 128) {
        float a = out_b[t];
#pragma unroll 8
        for (int k4 = 0; k4 < 32; ++k4) a += dot4(z4[k4], ows[k4 * 132 + t]);
        meta[(size_t)bp * Ff + t] = a;
    }
}

// ---------------- Kernel 3b: mpa attention + qia + base, per b ----------
__global__ __launch_bounds__(256) void k_mpa_post(
    const float* __restrict__ qkv, const float* __restrict__ meta,
    const float* __restrict__ query,
    const float* __restrict__ out_w, const float* __restrict__ out_b,
    const float* __restrict__ qia_in_w, const float* __restrict__ qia_in_b,
    const float* __restrict__ qia_out_w, const float* __restrict__ qia_out_b,
    const float* __restrict__ score_w, const float* __restrict__ score_b,
    float* __restrict__ basev)
{
    __shared__ float4 qs[16 * 33];
    __shared__ float4 ks[16 * 33];
    __shared__ float4 vs[16 * 33];
    __shared__ float Ss[16 * 17];
    __shared__ float wj[16];
    __shared__ float4 z4[32];
    __shared__ float4 mm4[32];
    __shared__ float v1s[128];
    __shared__ float4 tq4[32];
    __shared__ float v2s[128];
    __shared__ float red[128];
    int t = threadIdx.x, b = blockIdx.x;
    float* vsf = (float*)vs;

    const float4* src = (const float4*)(qkv + (size_t)b * 6144);
    for (int idx = t; idx < 1536; idx += 256) {
        int i = idx / 96, q = idx - i * 96;
        float4 v = src[idx];
        if (q < 32)       qs[i * 33 + q]        = v;
        else if (q < 64)  ks[i * 33 + (q - 32)] = v;
        else              vs[i * 33 + (q - 64)] = v;
    }
    float mmacc = 0.f;
    if (t < 128) {
#pragma unroll
        for (int p = 0; p < 16; ++p) mmacc += meta[(size_t)b * 2048 + p * 128 + t];
        mmacc *= (1.0f / 16.0f);
    }
    __syncthreads();

    {
        int si = t >> 4, sj = t & 15;
        float s = 0.f;
#pragma unroll 8
        for (int dq = 0; dq < 32; ++dq)
            s += dot4(qs[si * 33 + dq], ks[sj * 33 + dq]);
        Ss[si * 17 + sj] = s * 0.08838834764831843f;
    }
    if (t < 128) ((float*)mm4)[t] = mmacc;
    __syncthreads();
    if (t < 16) {
        float mx = -1e30f;
        for (int j = 0; j < 16; ++j) mx = fmaxf(mx, Ss[t * 17 + j]);
        float e[16]; float sum = 0.f;
        for (int j = 0; j < 16; ++j) { e[j] = expf(Ss[t * 17 + j] - mx); sum += e[j]; }
        float inv = 1.0f / sum;
        for (int j = 0; j < 16; ++j) Ss[t * 17 + j] = e[j] * inv;
    }
    __syncthreads();
    if (t < 16) {
        float s = 0.f;
        for (int i2 = 0; i2 < 16; ++i2) s += Ss[i2 * 17 + t];
        wj[t] = s * (1.0f / 16.0f);
    }
    __syncthreads();
    if (t < 128) {
        float s = 0.f;
#pragma unroll
        for (int j = 0; j < 16; ++j) s += wj[j] * vsf[j * 132 + t];
        ((float*)z4)[t] = s;
    }
    __syncthreads();

    if (t < 128) {
        const float4* w = (const float4*)(out_w) + (size_t)t * 32;
        float a = out_b[t];
#pragma unroll 8
        for (int dq = 0; dq < 32; ++dq) a += dot4(z4[dq], w[dq]);
        v1s[t] = a;
    } else {
        int f = t - 128;
        const float4* w = (const float4*)(qia_in_w) + (size_t)(256 + f) * 32;
        float a = qia_in_b[256 + f];
#pragma unroll 8
        for (int dq = 0; dq < 32; ++dq) a += dot4(mm4[dq], w[dq]);
        ((float*)tq4)[f] = a;
    }
    __syncthreads();
    if (t < 128) {
        const float4* w = (const float4*)(qia_out_w) + (size_t)t * 32;
        float a = qia_out_b[t];
#pragma unroll 8
        for (int dq = 0; dq < 32; ++dq) a += dot4(tq4[dq], w[dq]);
        v2s[t] = a;
    }
    __syncthreads();
    if (t < 128) {
        red[t] = query[(size_t)b * Dd + t] * score_w[t]
               + v1s[t] * score_w[128 + t]
               + v2s[t] * score_w[256 + t];
    }
    __syncthreads();
    for (int s = 64; s > 0; s >>= 1) {
        if (t < s) red[t] += red[t + s];
        __syncthreads();
    }
    if (t == 0) basev[b] = red[0] + score_b[0];
}

// ---------------- Kernel 4: exp(dot+base) with mask, per-b sum -----------
// grid = B*4 = 64 blocks, 256 threads; each block handles 4096 scores
// (4 consecutive p's of one b) as 1024 float4.
__global__ __launch_bounds__(256) void k_exp_sum(
    const float* __restrict__ dots, const int* __restrict__ cand_len,
    const float* __restrict__ basev, float* __restrict__ eout,
    float* __restrict__ sumexp)
{
    int blk = blockIdx.x;
    int b = blk >> 2, q = blk & 3;
    int t = threadIdx.x;
    float bb = basev[b];
    size_t off = (size_t)b * 16384 + (size_t)q * 4096;
    const float4* d4 = (const float4*)(dots + off);
    float4* o4 = (float4*)(eout + off);
    float lsum = 0.f;
#pragma unroll
    for (int r = 0; r < 4; ++r) {
        int idx4 = t + 256 * r;            // 0..1023
        int p = q * 4 + (idx4 >> 8);       // global p within b
        int c0 = (idx4 & 255) * 4;         // candidate index of .x
        int clen = cand_len[b * Pp + p];
        float4 v = d4[idx4];
        float4 e;
        e.x = (c0 + 0 < clen) ? expf(v.x + bb) : 0.f;
        e.y = (c0 + 1 < clen) ? expf(v.y + bb) : 0.f;
        e.z = (c0 + 2 < clen) ? expf(v.z + bb) : 0.f;
        e.w = (c0 + 3 < clen) ? expf(v.w + bb) : 0.f;
        o4[idx4] = e;
        lsum += e.x + e.y + e.z + e.w;
    }
    __shared__ float red[256];
    red[t] = lsum;
    __syncthreads();
    for (int s = 128; s > 0; s >>= 1) {
        if (t < s) red[t] += red[t + s];
        __syncthreads();
    }
    if (t == 0) atomicAdd(&sumexp[b], red[0]);
}

// ---------------- Kernel 5: normalize ------------------------------------
__global__ __launch_bounds__(256) void k_norm(
    float* __restrict__ out, const float* __restrict__ sumexp)
{
    int idx = blockIdx.x * 256 + threadIdx.x;
    int b = idx >> 12;  // 4096 float4 per batch
    float inv = 1.0f / sumexp[b];
    float4* o4 = (float4*)out;
    float4 v = o4[idx];
    v.x *= inv; v.y *= inv; v.z *= inv; v.w *= inv;
    o4[idx] = v;
}

extern "C" void kernel_launch(void* const* d_in, const int* in_sizes, int n_in,
                              void* d_out, int out_size, void* d_ws, size_t ws_size,
                              hipStream_t stream)
{
    const float* query    = (const float*)d_in[0];
    const float* path_emb = (const float*)d_in[1];
    const int*   path_len = (const int*)  d_in[2];
    const float* cand_emb = (const float*)d_in[3];
    const int*   cand_len = (const int*)  d_in[4];
    const float* conv_w   = (const float*)d_in[5];
    const float* conv_b   = (const float*)d_in[6];
    const float* pia_in_w = (const float*)d_in[7];
    const float* pia_in_b = (const float*)d_in[8];
    const float* pia_out_w= (const float*)d_in[9];
    const float* pia_out_b= (const float*)d_in[10];
    const float* mpa_in_w = (const float*)d_in[11];
    const float* mpa_in_b = (const float*)d_in[12];
    const float* mpa_out_w= (const float*)d_in[13];
    const float* mpa_out_b= (const float*)d_in[14];
    const float* qia_in_w = (const float*)d_in[15];
    const float* qia_in_b = (const float*)d_in[16];
    const float* qia_out_w= (const float*)d_in[17];
    const float* qia_out_b= (const float*)d_in[18];
    const float* score_w  = (const float*)d_in[19];
    const float* score_b  = (const float*)d_in[20];
    float* out = (float*)d_out;

    float* ws      = (float*)d_ws;
    float* inst    = ws;                        // B*P*I*F = 524288 floats
    float* meta    = ws + 524288;               // B*P*F   = 32768
    float* basev   = ws + 524288 + 32768;       // 16
    float* sumexp  = basev + 16;                // 16
    float* qkv_pia = sumexp + 16;               // 4096*384 = 1572864
    float* qkv_mpa = qkv_pia + 1572864;         // 256*384  = 98304
    float* dots    = qkv_mpa + 98304;           // B*P*C    = 262144

    // 1) fused: masked-mean+conv (4096 blocks) + cand dots (2048 blocks)
    k_front<<<4096 + 2048, 256, 0, stream>>>(path_emb, path_len, conv_w, conv_b,
                                             cand_emb, score_w,
                                             inst, dots, sumexp);
    // 2) pia qkv: M=4096, N=384 -> 64 x 4 = 256 blocks
    k_gemm<<<64 * 4, 256, 0, stream>>>(inst, pia_in_w, pia_in_b, qkv_pia, 384, 4);
    // 3) pia attention + mean + out-proj
    k_pia_post<<<Bb * Pp, 256, 0, stream>>>(qkv_pia, pia_out_w, pia_out_b, meta);
    // 4) mpa qkv: M=256, N=384 -> 4 x 4 = 16 blocks
    k_gemm<<<4 * 4, 256, 0, stream>>>(meta, mpa_in_w, mpa_in_b, qkv_mpa, 384, 4);
    // 5) mpa attention + qia + per-b base scalar
    k_mpa_post<<<Bb, 256, 0, stream>>>(qkv_mpa, meta, query,
                                       mpa_out_w, mpa_out_b,
                                       qia_in_w, qia_in_b, qia_out_w, qia_out_b,
                                       score_w, score_b, basev);
    // 6) exp(dot+base) masked + per-b sums
    k_exp_sum<<<Bb * 4, 256, 0, stream>>>(dots, cand_len, basev, out, sumexp);
    // 7) normalize
    k_norm<<<256, 256, 0, stream>>>(out, sumexp);
}